// Round 2
// baseline (187.353 us; speedup 1.0000x reference)
//
#include <hip/hip_runtime.h>
#include <cstdint>
#include <cstddef>

#define BATCH 8
#define NODES 2048
#define IN_DIM 64
#define DTOT 128
#define NKEY 1024
#define QGROUPS 128    // 2048/16 row-groups per batch
#define KGROUPS 64     // 1024/16 u-groups per batch
#define SROW 1028      // score LDS row stride (f32): 2-way bank aliasing only (free)

typedef _Float16 half8v __attribute__((ext_vector_type(8)));
typedef float float4v __attribute__((ext_vector_type(4)));

__device__ __forceinline__ unsigned long long make_key(float v, int idx) {
    unsigned u = __float_as_uint(v);
    u = (u & 0x80000000u) ? ~u : (u | 0x80000000u);
    return ((unsigned long long)u << 32) | (unsigned)(1023 - idx);
}

__device__ __forceinline__ float key_val(unsigned hi) {
    return __uint_as_float((hi & 0x80000000u) ? (hi & 0x7fffffffu) : ~hi);
}

// nontemporal float4 store: adj is written once and never re-read -> keep it out of L2
// so the per-XCD k-planes (512 KB, re-read by 128 blocks) stay L2-resident.
__device__ __forceinline__ void ntst4(float* p, float4v v) {
    __builtin_nontemporal_store(v, (float4v*)p);
}

// rare-path exact top-32 of a row held as vv[4] float4 per lane (elements jj*256+l*4+e)
__device__ __forceinline__ void fallback_select(const float4* vv, int l,
                                                bool& win, float& wval, int& widx) {
    float vals[16];
    #pragma unroll
    for (int jj = 0; jj < 4; ++jj) {
        vals[jj * 4 + 0] = vv[jj].x; vals[jj * 4 + 1] = vv[jj].y;
        vals[jj * 4 + 2] = vv[jj].z; vals[jj * 4 + 3] = vv[jj].w;
    }
    float selv = 0.f; int seli = 0;
    #pragma unroll 1
    for (int it = 0; it < 32; ++it) {
        float bv = -3.4e38f; int bi = 0x7fffffff;
        #pragma unroll
        for (int s = 0; s < 16; ++s) {
            int idx2 = (s >> 2) * 256 + l * 4 + (s & 3);
            if (vals[s] > bv) { bv = vals[s]; bi = idx2; }
        }
        #pragma unroll
        for (int off = 1; off < 64; off <<= 1) {
            float ov = __shfl_xor(bv, off, 64);
            int oi = __shfl_xor(bi, off, 64);
            if (ov > bv || (ov == bv && oi < bi)) { bv = ov; bi = oi; }
        }
        if (l == it) { selv = bv; seli = bi; }
        if (((bi >> 2) & 63) == l) {
            int slot = ((bi >> 8) << 2) + (bi & 3);
            #pragma unroll
            for (int s = 0; s < 16; ++s) if (s == slot) vals[s] = -3.4e38f;
        }
    }
    if (l < 32) { win = true; wval = selv; widx = seli; }
}

// ---------------- Kernel 1: projection -> split-fp16 planes in MFMA-fragment layout ----------------
// Fragment layout: plane[b][g][h][l][e], flat = ((bG + g)*4 + h)*512 + l*8 + e
// q is pre-scaled by 1/sqrt(32) (k by 1.0 -> bit-exact) so the score epilogue drops 4 muls/elem.
__global__ __launch_bounds__(256) void proj_qk(
    const float* __restrict__ x, const float* __restrict__ Wq, const float* __restrict__ bq,
    const float* __restrict__ Wk, const float* __restrict__ bk,
    _Float16* __restrict__ qfh, _Float16* __restrict__ qfl,
    _Float16* __restrict__ kfh, _Float16* __restrict__ kfl)
{
    __shared__ float xs[64 * 68];
    __shared__ float wsh[64 * 68];

    const int t = threadIdx.x;
    const int blk = blockIdx.x;
    const int b = blk / 96;
    const int idx = blk - b * 96;

    const float* W; const float* bias;
    _Float16* oh; _Float16* ol;
    int nbase, cbase; size_t gbase;
    float scale;
    if (idx < 64) {
        int nt = idx >> 1, ct = idx & 1;
        nbase = nt * 64; cbase = ct * 64;
        W = Wq; bias = bq; oh = qfh; ol = qfl;
        gbase = (size_t)b * QGROUPS + (nbase >> 4);
        scale = 0.17677669529663687f;   // 1/sqrt(32)
    } else {
        int i2 = idx - 64;
        int nt = i2 >> 1, ct = i2 & 1;
        nbase = nt * 64; cbase = ct * 64;
        W = Wk; bias = bk; oh = kfh; ol = kfl;
        gbase = (size_t)b * KGROUPS + (nbase >> 4);
        scale = 1.0f;                   // exact no-op for k
    }
    const int hbase = cbase >> 5;

    #pragma unroll
    for (int rep = 0; rep < 4; ++rep) {
        int f = rep * 256 + t;
        int r = f >> 4, d4 = f & 15;
        float4 xv = *(const float4*)(x + ((size_t)(b * NODES + nbase + r)) * IN_DIM + d4 * 4);
        *(float4*)(xs + r * 68 + d4 * 4) = xv;
        float4 wv = *(const float4*)(W + (size_t)(cbase + r) * IN_DIM + d4 * 4);
        *(float4*)(wsh + r * 68 + d4 * 4) = wv;
    }
    __syncthreads();

    const int w = t >> 6, l = t & 63;
    const int n_sel = w * 4 + (l >> 4);
    const int ul = l & 15;

    float acc[4][4];
    #pragma unroll
    for (int i = 0; i < 4; ++i)
        #pragma unroll
        for (int j = 0; j < 4; ++j) acc[i][j] = 0.f;

    #pragma unroll
    for (int d4 = 0; d4 < 16; ++d4) {
        float4 xv[4], wv[4];
        #pragma unroll
        for (int i = 0; i < 4; ++i)
            xv[i] = *(const float4*)(xs + (n_sel * 4 + i) * 68 + d4 * 4);
        #pragma unroll
        for (int j = 0; j < 4; ++j)
            wv[j] = *(const float4*)(wsh + (j * 16 + ul) * 68 + d4 * 4);
        #pragma unroll
        for (int i = 0; i < 4; ++i)
            #pragma unroll
            for (int j = 0; j < 4; ++j)
                acc[i][j] += xv[i].x * wv[j].x + xv[i].y * wv[j].y +
                             xv[i].z * wv[j].z + xv[i].w * wv[j].w;
    }
    __syncthreads();   // reuse xs as the 64x64 fp32 result tile

    #pragma unroll
    for (int j = 0; j < 4; ++j) {
        float bv = bias[cbase + j * 16 + ul];
        #pragma unroll
        for (int i = 0; i < 4; ++i)
            xs[(n_sel * 4 + i) * 68 + j * 16 + ul] = (acc[i][j] + bv) * scale;
    }
    __syncthreads();

    #pragma unroll
    for (int rep = 0; rep < 2; ++rep) {
        int u = rep * 256 + t;
        int g = u >> 7, hh = (u >> 6) & 1, lf = u & 63;
        const float* src = xs + (g * 16 + (lf & 15)) * 68 + hh * 32 + (lf >> 4) * 8;
        float4 f0 = *(const float4*)src;
        float4 f1 = *(const float4*)(src + 4);
        float tmp[8] = {f0.x, f0.y, f0.z, f0.w, f1.x, f1.y, f1.z, f1.w};
        half8v hv, lv;
        #pragma unroll
        for (int e = 0; e < 8; ++e) {
            _Float16 hi = (_Float16)tmp[e];
            hv[e] = hi;
            lv[e] = (_Float16)(tmp[e] - (float)hi);
        }
        size_t dst = ((gbase + g) * 4 + hbase + hh) * (size_t)512 + lf * 8;
        *(half8v*)(oh + dst) = hv;
        *(half8v*)(ol + dst) = lv;
    }
}

// ---------------- Kernel 2: fused MFMA scores + ballot top-32 + final row write ----------------
// Block: 16 n-rows x 1024 u, 512 threads (8 waves). Wave w: u-strip [w*128, w*128+128) in the
// score phase (depth-1 B prefetch), rows {2w, 2w+1} in the select phase. b = blk&7 -> XCD affinity.
// All adj stores are nontemporal so the 134 MB write stream does not evict the per-XCD k-planes.
// The two rows of the select phase run INTERLEAVED: their ~74 dependent ballot rounds are
// independent chains, so pairing them doubles ILP on the latency-bound v_cmp->vcc->SALU hops.
__global__ __launch_bounds__(512, 4) void scores_topk(
    const _Float16* __restrict__ qfh, const _Float16* __restrict__ qfl,
    const _Float16* __restrict__ kfh, const _Float16* __restrict__ kfl,
    const float* __restrict__ mlpw, const float* __restrict__ mlpb,
    float* __restrict__ adj)
{
    __shared__ float sc[16 * SROW];               // 64.25 KB scores
    __shared__ unsigned long long cand[2][8][64]; // 8 KB candidate buffers (per row-slot)

    const int t = threadIdx.x;
    const int blk = blockIdx.x;
    const int b = blk & 7;                     // batch == XCD affinity (k stays L2-hot)
    const int gq = blk >> 3;                   // q row-group (16 rows)

    const int w = t >> 6, l = t & 63;
    const int quad = l >> 4, lane16 = l & 15;

    // A fragments: coalesced 16B loads from fragment-layout q
    half8v Ah[4], Al[4];
    #pragma unroll
    for (int h = 0; h < 4; ++h) {
        size_t a = (((size_t)b * QGROUPS + gq) * 4 + h) * 512 + l * 8;
        Ah[h] = *(const half8v*)(qfh + a);
        Al[h] = *(const half8v*)(qfl + a);
    }

    // uniform scalar loads -> SGPRs (no VGPR cost in the hot loop)
    float mwv[4][4], mbv[4];
    #pragma unroll
    for (int o = 0; o < 4; ++o) {
        mbv[o] = mlpb[o];
        #pragma unroll
        for (int h = 0; h < 4; ++h) mwv[o][h] = mlpw[o * 4 + h];
    }

    // base for interleaved upper-half zero writes (cols [1024,2048) of this block's 16 rows)
    const size_t zbase = ((size_t)(b * NODES + gq * 16)) * NODES + NKEY;
    const float4v z4 = {0.f, 0.f, 0.f, 0.f};

    // ---- score phase with depth-1 software pipeline on B fragments ----
    half8v Bh[4], Bl[4];
    {
        size_t a0 = (((size_t)b * KGROUPS + w * 8) * 4) * (size_t)512 + l * 8;
        #pragma unroll
        for (int h = 0; h < 4; ++h) {
            Bh[h] = *(const half8v*)(kfh + a0 + h * 512);
            Bl[h] = *(const half8v*)(kfl + a0 + h * 512);
        }
    }

    #pragma unroll
    for (int i = 0; i < 8; ++i) {
        const int g = w * 8 + i;               // u-group
        half8v Bhn[4], Bln[4];
        if (i < 7) {                           // prefetch next u-group while MFMAs run
            size_t a1 = (((size_t)b * KGROUPS + g + 1) * 4) * (size_t)512 + l * 8;
            #pragma unroll
            for (int h = 0; h < 4; ++h) {
                Bhn[h] = *(const half8v*)(kfh + a1 + h * 512);
                Bln[h] = *(const half8v*)(kfl + a1 + h * 512);
            }
        }

        // interleaved nontemporal zero-store: 16 rows x 1024 upper cols, 512 thr x 8 iters
        {
            int f = i * 512 + t;
            ntst4(adj + zbase + (size_t)(f >> 8) * NODES + (f & 255) * 4, z4);
        }

        float4v C[4];
        #pragma unroll
        for (int h = 0; h < 4; ++h) {
            float4v c = {0.f, 0.f, 0.f, 0.f};
            c = __builtin_amdgcn_mfma_f32_16x16x32_f16(Ah[h], Bh[h], c, 0, 0, 0);
            c = __builtin_amdgcn_mfma_f32_16x16x32_f16(Ah[h], Bl[h], c, 0, 0, 0);
            c = __builtin_amdgcn_mfma_f32_16x16x32_f16(Al[h], Bh[h], c, 0, 0, 0);
            C[h] = c;
        }

        // scalar epilogue: ssum = sum_h a_h + sum_o relu(mlp_o . a + b_o)
        const int col = g * 16 + lane16;
        #pragma unroll
        for (int e = 0; e < 4; ++e) {
            float a0 = C[0][e], a1 = C[1][e], a2 = C[2][e], a3 = C[3][e];
            float ssum = ((a0 + a1) + a2) + a3;
            #pragma unroll
            for (int o = 0; o < 4; ++o) {
                float to = fmaf(a3, mwv[o][3],
                           fmaf(a2, mwv[o][2],
                           fmaf(a1, mwv[o][1],
                           fmaf(a0, mwv[o][0], mbv[o]))));
                ssum += fmaxf(to, 0.f);
            }
            sc[(quad * 4 + e) * SROW + col] = ssum;
        }

        if (i < 7) {
            #pragma unroll
            for (int h = 0; h < 4; ++h) { Bh[h] = Bhn[h]; Bl[h] = Bln[h]; }
        }
    }
    __syncthreads();

    // ---- top-32: wave w handles rows 2w and 2w+1 with their serial chains interleaved ----
    const int row0 = w * 2, row1 = w * 2 + 1;
    float* R0 = sc + row0 * SROW;
    float* R1 = sc + row1 * SROW;

    float4 v0[4], v1[4];   // lane l holds u-indices jj*256 + l*4 + e
    #pragma unroll
    for (int jj = 0; jj < 4; ++jj) {
        v0[jj] = *(const float4*)(R0 + jj * 256 + l * 4);
        v1[jj] = *(const float4*)(R1 + jj * 256 + l * 4);
    }

    float m0 = v0[0].x, m1 = v1[0].x;
    #pragma unroll
    for (int jj = 0; jj < 4; ++jj) {
        m0 = fmaxf(m0, v0[jj].x); m0 = fmaxf(m0, v0[jj].y);
        m0 = fmaxf(m0, v0[jj].z); m0 = fmaxf(m0, v0[jj].w);
        m1 = fmaxf(m1, v1[jj].x); m1 = fmaxf(m1, v1[jj].y);
        m1 = fmaxf(m1, v1[jj].z); m1 = fmaxf(m1, v1[jj].w);
    }

    // T = 32nd-largest lane-max per row, exact, via interleaved bitwise ballot search
    unsigned km0, km1;
    { unsigned s = __float_as_uint(m0); km0 = (s & 0x80000000u) ? ~s : (s | 0x80000000u); }
    { unsigned s = __float_as_uint(m1); km1 = (s & 0x80000000u) ? ~s : (s | 0x80000000u); }
    unsigned accT0 = 0u, accT1 = 0u;
    #pragma unroll
    for (int bit = 31; bit >= 0; --bit) {
        unsigned tr0 = accT0 | (1u << bit);
        unsigned tr1 = accT1 | (1u << bit);
        unsigned long long b0 = __ballot(km0 >= tr0);
        unsigned long long b1 = __ballot(km1 >= tr1);
        if (__popcll(b0) >= 32) accT0 = tr0;
        if (__popcll(b1) >= 32) accT1 = tr1;
    }
    const float T0 = key_val(accT0);   // >= 32 row elements are >= T, T <= true 32nd value
    const float T1 = key_val(accT1);

    // ballot-compact candidates >= T into cand[r][w][]
    cand[0][w][l] = 0ull;
    cand[1][w][l] = 0ull;
    __builtin_amdgcn_wave_barrier();
    int tot0 = 0, tot1 = 0;
    #pragma unroll
    for (int jj = 0; jj < 4; ++jj) {
        #pragma unroll
        for (int e = 0; e < 4; ++e) {
            float va = (e == 0) ? v0[jj].x : (e == 1) ? v0[jj].y : (e == 2) ? v0[jj].z : v0[jj].w;
            float vb = (e == 0) ? v1[jj].x : (e == 1) ? v1[jj].y : (e == 2) ? v1[jj].z : v1[jj].w;
            bool p0 = (va >= T0), p1 = (vb >= T1);
            unsigned long long mk0 = __ballot(p0);
            unsigned long long mk1 = __ballot(p1);
            int idx = jj * 256 + l * 4 + e;
            if (p0) {
                int pos = tot0 + __popcll(mk0 & ((1ull << l) - 1ull));
                if (pos < 64) cand[0][w][pos] = make_key(va, idx);
            }
            if (p1) {
                int pos = tot1 + __popcll(mk1 & ((1ull << l) - 1ull));
                if (pos < 64) cand[1][w][pos] = make_key(vb, idx);
            }
            tot0 += (int)__popcll(mk0);
            tot1 += (int)__popcll(mk1);
        }
    }
    __builtin_amdgcn_wave_barrier();

    bool win0 = false, win1 = false;
    float wval0 = 0.f, wval1 = 0.f;
    int widx0 = 0, widx1 = 0;

    // common case: both candidate sets fit 64 keys -> interleaved radix-ballot select
    {
        unsigned long long k0 = cand[0][w][l], k1 = cand[1][w][l];
        unsigned hi0 = (unsigned)(k0 >> 32), lo0 = (unsigned)k0;
        unsigned hi1 = (unsigned)(k1 >> 32), lo1 = (unsigned)k1;

        unsigned X0 = 0u, X1 = 0u;
        #pragma unroll
        for (int bit = 31; bit >= 0; --bit) {
            unsigned tr0 = X0 | (1u << bit);
            unsigned tr1 = X1 | (1u << bit);
            unsigned long long b0 = __ballot(hi0 >= tr0);
            unsigned long long b1 = __ballot(hi1 >= tr1);
            if (__popcll(b0) >= 32) X0 = tr0;
            if (__popcll(b1) >= 32) X1 = tr1;
        }
        int rem0 = 32 - __popcll(__ballot(hi0 > X0));
        int rem1 = 32 - __popcll(__ballot(hi1 > X1));
        unsigned Y0 = 0u, Y1 = 0u;
        #pragma unroll
        for (int bit = 9; bit >= 0; --bit) {
            unsigned tr0 = Y0 | (1u << bit);
            unsigned tr1 = Y1 | (1u << bit);
            unsigned long long b0 = __ballot(hi0 == X0 && lo0 >= tr0);
            unsigned long long b1 = __ballot(hi1 == X1 && lo1 >= tr1);
            if (__popcll(b0) >= rem0) Y0 = tr0;
            if (__popcll(b1) >= rem1) Y1 = tr1;
        }
        if (tot0 <= 64 && (hi0 > X0 || (hi0 == X0 && lo0 >= Y0))) {
            win0 = true; wval0 = key_val(hi0); widx0 = 1023 - (int)lo0;
        }
        if (tot1 <= 64 && (hi1 > X1 || (hi1 == X1 && lo1 >= Y1))) {
            win1 = true; wval1 = key_val(hi1); widx1 = 1023 - (int)lo1;
        }
    }
    // rare fallback(s): exact 32-round butterfly extraction (wave-uniform branch)
    if (tot0 > 64) { win0 = false; fallback_select(v0, l, win0, wval0, widx0); }
    if (tot1 > 64) { win1 = false; fallback_select(v1, l, win1, wval1, widx1); }

    // rebuild both rows in place (DS pipe is in-order per wave): b128 zeros, scatter winners
    __builtin_amdgcn_wave_barrier();
    #pragma unroll
    for (int jj = 0; jj < 4; ++jj) {
        *(float4v*)(R0 + jj * 256 + l * 4) = z4;
        *(float4v*)(R1 + jj * 256 + l * 4) = z4;
    }
    __builtin_amdgcn_wave_barrier();
    if (win0) R0[widx0] = wval0;
    if (win1) R1[widx1] = wval1;
    __builtin_amdgcn_wave_barrier();

    // final coalesced nontemporal writes: lower 1024 cols (upper half zeroed in score phase)
    float* rp0 = adj + ((size_t)(b * NODES + gq * 16 + row0)) * NODES;
    float* rp1 = adj + ((size_t)(b * NODES + gq * 16 + row1)) * NODES;
    #pragma unroll
    for (int jj = 0; jj < 4; ++jj) {
        int c4 = jj * 64 + l;
        ntst4(rp0 + c4 * 4, *(const float4v*)(R0 + c4 * 4));
        ntst4(rp1 + c4 * 4, *(const float4v*)(R1 + c4 * 4));
    }
}

extern "C" void kernel_launch(void* const* d_in, const int* in_sizes, int n_in,
                              void* d_out, int out_size, void* d_ws, size_t ws_size,
                              hipStream_t stream) {
    const float* x    = (const float*)d_in[0];
    const float* Wq   = (const float*)d_in[1];
    const float* bq   = (const float*)d_in[2];
    const float* Wk   = (const float*)d_in[3];
    const float* bk   = (const float*)d_in[4];
    const float* mlpw = (const float*)d_in[5];
    const float* mlpb = (const float*)d_in[6];
    // ln_g, ln_b feed only the deleted adj_static -> unused.

    _Float16* qfh = (_Float16*)d_ws;                        // 4 MB
    _Float16* qfl = qfh + (size_t)BATCH * NODES * DTOT;     // 4 MB
    _Float16* kfh = qfl + (size_t)BATCH * NODES * DTOT;     // 2 MB
    _Float16* kfl = kfh + (size_t)BATCH * NKEY * DTOT;      // 2 MB (total 12 MB)
    float* adj = (float*)d_out;

    proj_qk<<<dim3(BATCH * 96), dim3(256), 0, stream>>>(x, Wq, bq, Wk, bk, qfh, qfl, kfh, kfl);
    scores_topk<<<dim3(BATCH * QGROUPS), dim3(512), 0, stream>>>(qfh, qfl, kfh, kfl, mlpw, mlpb, adj);
}